// Round 8
// baseline (322.588 us; speedup 1.0000x reference)
//
#include <hip/hip_runtime.h>
#include <math.h>

// Problem constants (fixed by setup_inputs): B=4, H=W=896, n_h=n_w=64,
// GS=8, GL=8, LS=16, LL=8, NA=12, ALPHA=0.5
#define HWPIX 802816            // 896*896
#define OUT_IL 9633792          // offset of I_local  (4*3*896*896)
#define OUT_GG 19267584         // offset of G_global
#define OUT_GL 19292160         // offset of G_local
#define OUT_G  19390464         // offset of g

// workspace layout (float offsets)
#define WS_WT4  0               // combined weight, packed [k/4][o][4], 256x640
#define WS_BC   163840          // combined bias, 256
#define WS_POOL 164096          // pooled [b][c][cell], 4*256*256
#define WS_GSEM 427264          // g_sem_patch, 4*4096
#define WS_RG   443648          // global grid [b][y][x][z][c], 4*8*8*8*12
#define WS_RL   468224          // local grid  [b][y][x][z][c], 4*16*16*8*12
#define WS_W1T  566528          // guide_w1 packed [kq][k4][hg][hl][4], 384*64
#define WS_LWT  591104          // local_w transposed [c][o], 256*96

__device__ __forceinline__ float fast_exp2(float x) {
  return __builtin_amdgcn_exp2f(x);
}
__device__ __forceinline__ float fast_log2(float x) {
  return __builtin_amdgcn_logf(x);  // v_log_f32 = log2(x)
}
__device__ __forceinline__ float srgb_lin(float v) {
  float p = fast_exp2(2.4f * fast_log2((v + 0.055f) * (1.0f / 1.055f)));
  return v > 0.04045f ? p : v * (1.0f / 12.92f);
}
__device__ __forceinline__ float labf(float t) {
  float c = fast_exp2((1.0f / 3.0f) * fast_log2(t));
  return t > 0.008856f ? c : 7.787f * t + (4.0f / 29.0f);
}

// ---------------------------------------------------------------------------
// K1: combined weight W[o][k] packed Wt4[(k>>2)*256+o][k&3]; bc = fused bias.
// block 641 packs guide_w1: w1T[kq][k4][hg][hl][4] (k = kq*96+k4*4+j,
// h = hg*16+hl). block 642 transposes local_w -> lwT.
__global__ __launch_bounds__(256) void k_prep(
    const float* __restrict__ fus_w, const float* __restrict__ fus_b,
    const float* __restrict__ dino_w, const float* __restrict__ dino_b,
    const float* __restrict__ gw1, const float* __restrict__ lw,
    float* __restrict__ Wt4, float* __restrict__ bc, float* __restrict__ w1T,
    float* __restrict__ lwT) {
  if (blockIdx.x == 642) {
    int t = threadIdx.x;
    for (int it = 0; it < 96; ++it) {
      int idx = it * 256 + t;       // over 96*256; o = idx>>8, c = idx&255
      int o = idx >> 8;
      int c = idx & 255;
      lwT[c * 96 + o] = lw[o * 256 + c];
    }
    return;
  }
  if (blockIdx.x == 641) {
    int t = threadIdx.x;
    for (int it = 0; it < 96; ++it) {
      int idx = it * 256 + t;       // idx over 384*64; k = idx>>6, h = idx&63
      int h = idx & 63;
      int k = idx >> 6;
      int kq = k / 96;              // 0..3
      int krem = k - kq * 96;
      int k4 = krem >> 2;           // 0..23
      int j = krem & 3;
      int hg = h >> 4, hl = h & 15;
      w1T[((((kq * 24 + k4) * 4 + hg) * 16) + hl) * 4 + j] = gw1[h * 384 + k];
    }
    return;
  }
  if (blockIdx.x == 640) {
    int o = threadIdx.x;
    float acc = fus_b[o];
    for (int m = 0; m < 128; ++m) acc += fus_w[o * 384 + 256 + m] * dino_b[m];
    bc[o] = acc;
    return;
  }
  int idx = blockIdx.x * 256 + threadIdx.x;
  int o = idx / 640;
  int k = idx - o * 640;
  float val;
  if (k < 256) {
    val = fus_w[o * 384 + k];
  } else {
    int d = k - 256;
    float acc = 0.0f;
    for (int m = 0; m < 128; ++m)
      acc += fus_w[o * 384 + 256 + m] * dino_w[m * 384 + d];
    val = acc;
  }
  Wt4[((k >> 2) * 256 + o) * 4 + (k & 3)] = val;
}

// ---------------------------------------------------------------------------
// K_MID (round-7, resubmitted after infra failure): pool + guide fused,
// UNIFORM 256-thread blocks so the whole mix stays co-resident (round-6's
// 512-thr/51KB blocks capped at ~2.5 blocks/CU -> Occupancy 20%, phases
// serialized, 75 us).
//   blocks 0..255     : pool, 4 cells/block, thread = output c with 4
//                       accumulators (Wt4 read once per 4 cells: 164 MB L2);
//                       LDS 10.2 KB; direct float4 pooled write (acc0..3 of
//                       thread c ARE 4 consecutive cells — no transpose).
//   blocks 256..1279  : guide, 16 patches/block (round-4 shape), 25.6 KB.
// 1280 blocks ~= 5/CU all-resident, ~20 waves/CU: pool staging latency,
// guide VALU, L2 service and DS reads interleave for the whole dispatch.
__global__ __launch_bounds__(256) void k_mid(
    const float* __restrict__ R, const float* __restrict__ F,
    const float* __restrict__ Wt4, const float* __restrict__ bc,
    const float* __restrict__ lwT, const float* __restrict__ lb,
    float* __restrict__ pooled, float* __restrict__ out4,
    float* __restrict__ rl,
    const float* __restrict__ w1T, const float* __restrict__ b1,
    const float* __restrict__ w2, const float* __restrict__ b2,
    float* __restrict__ gsem) {
  __shared__ float4 sbuf4[1600];   // 25.6 KB: guide 16x4x25; pool uses 2560 f
  float* s = (float*)sbuf4;
  int blk = blockIdx.x;
  int t = threadIdx.x;

  if (blk >= 256) {
    // ---------------- guide path (blocks 256..1279) ----------------
    int gb = blk - 256;
    int pb = gb * 16;                // 16 patches staged
    const float4* Fb = (const float4*)(F + (size_t)pb * 384);
#pragma unroll
    for (int r6 = 0; r6 < 6; ++r6) {
      int g = r6 * 256 + t;          // 0..1535 over [16 rows][96 vec4]
      int row = g / 96;
      int col = g - row * 96;
      int cq = col / 24;
      int c4 = col - cq * 24;
      sbuf4[(row * 4 + cq) * 25 + c4] = Fb[g];
    }
    __syncthreads();
    int wave = t >> 6;
    int lane = t & 63;
    int kq = lane >> 4;
    int hl = lane & 15;
    float acc[4][4];               // [patch][hidden-group]
#pragma unroll
    for (int p = 0; p < 4; ++p)
#pragma unroll
      for (int hg = 0; hg < 4; ++hg) acc[p][hg] = 0.0f;
    const float4* w4 = (const float4*)w1T;
    int prow = wave * 4;
    for (int k4 = 0; k4 < 24; ++k4) {
      float4 wv0 = w4[((kq * 24 + k4) * 4 + 0) * 16 + hl];
      float4 wv1 = w4[((kq * 24 + k4) * 4 + 1) * 16 + hl];
      float4 wv2 = w4[((kq * 24 + k4) * 4 + 2) * 16 + hl];
      float4 wv3 = w4[((kq * 24 + k4) * 4 + 3) * 16 + hl];
#pragma unroll
      for (int p = 0; p < 4; ++p) {
        float4 fv = sbuf4[((prow + p) * 4 + kq) * 25 + k4];
        acc[p][0] += fv.x * wv0.x + fv.y * wv0.y + fv.z * wv0.z + fv.w * wv0.w;
        acc[p][1] += fv.x * wv1.x + fv.y * wv1.y + fv.z * wv1.z + fv.w * wv1.w;
        acc[p][2] += fv.x * wv2.x + fv.y * wv2.y + fv.z * wv2.z + fv.w * wv2.w;
        acc[p][3] += fv.x * wv3.x + fv.y * wv3.y + fv.z * wv3.z + fv.w * wv3.w;
      }
    }
#pragma unroll
    for (int p = 0; p < 4; ++p)
#pragma unroll
      for (int hg = 0; hg < 4; ++hg) {
        float v = acc[p][hg];
        v += __shfl_xor(v, 16, 64);
        v += __shfl_xor(v, 32, 64);
        acc[p][hg] = v;
      }
    float b1v[4], w2v[4];
#pragma unroll
    for (int hg = 0; hg < 4; ++hg) {
      b1v[hg] = b1[hg * 16 + hl];
      w2v[hg] = w2[hg * 16 + hl];
    }
    float b2v = b2[0];
    float res = 0.0f;
#pragma unroll
    for (int p = 0; p < 4; ++p) {
      float v = 0.0f;
#pragma unroll
      for (int hg = 0; hg < 4; ++hg)
        v += fmaxf(acc[p][hg] + b1v[hg], 0.0f) * w2v[hg];
#pragma unroll
      for (int m = 8; m >= 1; m >>= 1) v += __shfl_xor(v, m, 64);
      if (lane == p) res = v;
    }
    if (lane < 4) gsem[pb + prow + lane] = 1.0f / (1.0f + expf(-(res + b2v)));
    return;
  }

  // ---------------- pool path (blocks 0..255, 4 cells/block) ----------------
  int b = blk >> 6;
  int i = (blk >> 2) & 15;
  int jg = blk & 3;
  int c = t;                // channel / output index, 0..255
  {  // R part: 4 cells
#pragma unroll
    for (int cell = 0; cell < 4; ++cell) {
      const float* rb = R + (((b * 256 + c) * 64 + i * 4) * 64) + (jg * 4 + cell) * 4;
      float p = 0.0f;
#pragma unroll
      for (int di = 0; di < 4; ++di) {
        float4 v = *(const float4*)(rb + di * 64);
        p += v.x + v.y + v.z + v.w;
      }
      s[cell * 640 + c] = p;
    }
  }
  {  // F part: 4 cells; thread covers k=256+c (and k=512+c for c<128)
#pragma unroll
    for (int cell = 0; cell < 4; ++cell) {
      float a0 = 0.0f, a1 = 0.0f;
      const float* fb = F + (size_t)(b * 4096 + (i * 4) * 64 + (jg * 4 + cell) * 4) * 384;
#pragma unroll
      for (int pix = 0; pix < 16; ++pix) {
        const float* fr = fb + (size_t)((pix >> 2) * 64 + (pix & 3)) * 384;
        a0 += fr[c];
        if (c < 128) a1 += fr[256 + c];
      }
      s[cell * 640 + 256 + c] = a0;
      if (c < 128) s[cell * 640 + 512 + c] = a1;
    }
  }
  __syncthreads();
  // kk-loop: one Wt4 float4 feeds 4 cell-FMAs
  float acc0 = 0.0f, acc1 = 0.0f, acc2 = 0.0f, acc3 = 0.0f;
  const float4* w4 = (const float4*)Wt4;
  const float4* s40 = (const float4*)(s + 0 * 640);
  const float4* s41 = (const float4*)(s + 1 * 640);
  const float4* s42 = (const float4*)(s + 2 * 640);
  const float4* s43 = (const float4*)(s + 3 * 640);
#pragma unroll 8
  for (int kk = 0; kk < 160; ++kk) {
    float4 wv = w4[kk * 256 + c];
    float4 v0 = s40[kk];
    float4 v1 = s41[kk];
    float4 v2 = s42[kk];
    float4 v3 = s43[kk];
    acc0 += wv.x * v0.x + wv.y * v0.y + wv.z * v0.z + wv.w * v0.w;
    acc1 += wv.x * v1.x + wv.y * v1.y + wv.z * v1.z + wv.w * v1.w;
    acc2 += wv.x * v2.x + wv.y * v2.y + wv.z * v2.z + wv.w * v2.w;
    acc3 += wv.x * v3.x + wv.y * v3.y + wv.z * v3.z + wv.w * v3.w;
  }
  float bco = bc[c];
  float p0 = acc0 * (1.0f / 16.0f) + bco;
  float p1 = acc1 * (1.0f / 16.0f) + bco;
  float p2 = acc2 * (1.0f / 16.0f) + bco;
  float p3 = acc3 * (1.0f / 16.0f) + bco;
  *(float4*)(pooled + ((size_t)(b * 256 + c) * 256) + i * 16 + jg * 4) =
      make_float4(p0, p1, p2, p3);
  __syncthreads();   // staging area free; stash pooled for glocal
  s[0 * 256 + c] = p0;
  s[1 * 256 + c] = p1;
  s[2 * 256 + c] = p2;
  s[3 * 256 + c] = p3;
  __syncthreads();
  // fused G_local: 4 cells x 96 outputs = 384 work items on 256 threads,
  // two passes.
#pragma unroll
  for (int half = 0; half < 2; ++half) {
    int idx = half * 256 + t;
    if (idx < 384) {
      int cl = idx / 96;            // 0..3
      int o = idx - cl * 96;        // 0..95
      const float* sc_ = s + cl * 256;
      float a2 = lb[o];
      for (int cc = 0; cc < 256; ++cc)
        a2 += lwT[cc * 96 + o] * sc_[cc];   // coalesced lanes, LDS broadcast
      int cellg = i * 16 + jg * 4 + cl;
      int n = o >> 3, l = o & 7;
      out4[((b * 12 + n) * 256 + cellg) * 8 + l] = a2;
      rl[b * 24576 + (cellg * 8 + l) * 12 + n] = a2;
    }
  }
}

// ---------------------------------------------------------------------------
// K3 (merged k_gap + k_gglobal): block = (b, og). Each block redundantly
// recomputes f_gap and h from L2-hot pooled/g1_w, then its 256-output g2
// slice.
__global__ __launch_bounds__(1024) void k_head(
    const float* __restrict__ pooled, const float* __restrict__ g1_w,
    const float* __restrict__ g1_b, const float* __restrict__ g2_w,
    const float* __restrict__ g2_b, float* __restrict__ out3,
    float* __restrict__ rg) {
  int b = blockIdx.x / 24;
  int og = (blockIdx.x % 24) * 256;
  int t = threadIdx.x;
  int ol = t & 255;
  int q = t >> 8;
  __shared__ float part[4][256];
  __shared__ float f[256];
  __shared__ float hv[256];
  {  // f_gap partials
    const float4* pr4 = (const float4*)(pooled + (size_t)(b * 256 + ol) * 256 + q * 64);
    float s = 0.0f;
#pragma unroll
    for (int i = 0; i < 16; ++i) {
      float4 v = pr4[i];
      s += v.x + v.y + v.z + v.w;
    }
    part[q][ol] = s;
  }
  __syncthreads();
  if (t < 256)
    f[t] = (part[0][t] + part[1][t] + part[2][t] + part[3][t]) * (1.0f / 256.0f);
  __syncthreads();
  {  // h = relu(g1_w @ f + g1_b)
    const float4* wr = (const float4*)(g1_w + (size_t)ol * 256 + q * 64);
    const float4* fq = (const float4*)(f + q * 64);
    float acc = 0.0f;
#pragma unroll
    for (int i = 0; i < 16; ++i) {
      float4 w = wr[i];
      float4 v = fq[i];
      acc += w.x * v.x + w.y * v.y + w.z * v.z + w.w * v.w;
    }
    part[q][ol] = acc;
  }
  __syncthreads();
  if (t < 256)
    hv[t] = fmaxf(part[0][t] + part[1][t] + part[2][t] + part[3][t] + g1_b[t], 0.0f);
  __syncthreads();
  {  // g2 slice
    const float4* wr = (const float4*)(g2_w + (size_t)(og + ol) * 256 + q * 64);
    const float4* hq = (const float4*)(hv + q * 64);
    float acc = 0.0f;
#pragma unroll
    for (int i = 0; i < 16; ++i) {
      float4 w = wr[i];
      float4 v = hq[i];
      acc += w.x * v.x + w.y * v.y + w.z * v.z + w.w * v.w;
    }
    part[q][ol] = acc;
  }
  __syncthreads();
  if (t < 256) {
    int o = og + t;
    float a = part[0][t] + part[1][t] + part[2][t] + part[3][t] + g2_b[o];
    out3[b * 6144 + o] = a;
    int n = o >> 9, y = (o >> 6) & 7, x = (o >> 3) & 7, z = o & 7;
    rg[b * 6144 + ((y * 8 + x) * 8 + z) * 12 + n] = a;
  }
}

// ---------------------------------------------------------------------------
// K6: per-pixel, one block per row; y-interp hoisted to LDS; img prefetch +
// batched staging. DS-pipe floor ~23.5 us (24 ds_read_b128/px algorithmic).
template <int SDIM>
__device__ __forceinline__ void slice_lds(
    const float* __restrict__ sg, int w, int z0, int z1, float wz,
    float r, float g, float bl, float& o0, float& o1, float& o2) {
  constexpr float sc = (float)(SDIM - 1) * (1.0f / 895.0f);
  float fxs = (float)w * sc;
  int x0 = (int)fxs;
  if (x0 > SDIM - 1) x0 = SDIM - 1;
  int x1 = x0 < SDIM - 1 ? x0 + 1 : SDIM - 1;
  float wx = fxs - (float)x0;
  float wz0 = 1.0f - wz;
  float w00 = (1.0f - wx) * wz0;
  float w01 = (1.0f - wx) * wz;
  float w10 = wx * wz0;
  float w11 = wx * wz;
  const float4* p00 = (const float4*)(sg + (x0 * 8 + z0) * 12);
  const float4* p01 = (const float4*)(sg + (x0 * 8 + z1) * 12);
  const float4* p10 = (const float4*)(sg + (x1 * 8 + z0) * 12);
  const float4* p11 = (const float4*)(sg + (x1 * 8 + z1) * 12);
  float a[12];
#pragma unroll
  for (int c = 0; c < 3; ++c) {
    float4 v00 = p00[c], v01 = p01[c], v10 = p10[c], v11 = p11[c];
    a[4 * c + 0] = w00 * v00.x + w01 * v01.x + w10 * v10.x + w11 * v11.x;
    a[4 * c + 1] = w00 * v00.y + w01 * v01.y + w10 * v10.y + w11 * v11.y;
    a[4 * c + 2] = w00 * v00.z + w01 * v01.z + w10 * v10.z + w11 * v11.z;
    a[4 * c + 3] = w00 * v00.w + w01 * v01.w + w10 * v10.w + w11 * v11.w;
  }
  o0 = fminf(fmaxf(a[0] * r + a[1] * g + a[2] * bl + a[9], 0.0f), 1.0f);
  o1 = fminf(fmaxf(a[3] * r + a[4] * g + a[5] * bl + a[10], 0.0f), 1.0f);
  o2 = fminf(fmaxf(a[6] * r + a[7] * g + a[8] * bl + a[11], 0.0f), 1.0f);
}

__global__ __launch_bounds__(448) void k_pixel(
    const float* __restrict__ img, const float* __restrict__ gsem,
    const float* __restrict__ rg, const float* __restrict__ rl,
    float* __restrict__ out) {
  int blk = blockIdx.x;
  int b = blk / 896;
  int h = blk - b * 896;
  int t = threadIdx.x;
  __shared__ float sgr[64];     // y-interp'd gsem row
  __shared__ float sG[768];     // y-interp'd global grid row [x][z][c]
  __shared__ float sL[1536];    // y-interp'd local grid row  [x][z][c]

  // ---- img prefetch: issue the 6 pixel loads first so HBM latency
  // overlaps the staging phase.
  int hwA = h * 896 + t;
  int hwB = hwA + 448;
  const float* imb = img + (size_t)b * 3 * HWPIX;
  float rrA = imb[hwA],             rrB = imb[hwB];
  float ggA = imb[HWPIX + hwA],     ggB = imb[HWPIX + hwB];
  float bbA = imb[2 * HWPIX + hwA], bbB = imb[2 * HWPIX + hwB];

  // y factors
  float sy = fminf(fmaxf((h + 0.5f) * (1.0f / 14.0f) - 0.5f, 0.0f), 63.0f);
  int y0s = (int)sy;
  int y1s = y0s < 63 ? y0s + 1 : 63;
  float wys = sy - (float)y0s;
  float fyg = (float)h * (7.0f / 895.0f);
  int y0g = (int)fyg;
  if (y0g > 7) y0g = 7;
  int y1g = y0g < 7 ? y0g + 1 : 7;
  float wyg = fyg - (float)y0g;
  float fyl = (float)h * (15.0f / 895.0f);
  int y0l = (int)fyl;
  if (y0l > 15) y0l = 15;
  int y1l = y0l < 15 ? y0l + 1 : 15;
  float wyl = fyl - (float)y0l;

  // ---- staging: batch all loads, then all LDS writes
  const float* g0 = rg + b * 6144 + y0g * 768;
  const float* g1 = rg + b * 6144 + y1g * 768;
  const float* l0 = rl + b * 24576 + y0l * 1536;
  const float* l1 = rl + b * 24576 + y1l * 1536;
  float ga0 = g0[t], gb0 = g1[t];
  float ga1 = 0.0f, gb1 = 0.0f;
  if (t < 320) { ga1 = g0[t + 448]; gb1 = g1[t + 448]; }
  float la0 = l0[t], lb0 = l1[t];
  float la1 = l0[t + 448], lb1 = l1[t + 448];
  float la2 = l0[t + 896], lb2s = l1[t + 896];
  float la3 = 0.0f, lb3 = 0.0f;
  if (t < 192) { la3 = l0[t + 1344]; lb3 = l1[t + 1344]; }
  float sg0 = 0.0f, sg1 = 0.0f;
  if (t < 64) {
    const float* gbp = gsem + b * 4096;
    sg0 = gbp[y0s * 64 + t];
    sg1 = gbp[y1s * 64 + t];
  }
  sG[t] = ga0 * (1.0f - wyg) + gb0 * wyg;
  if (t < 320) sG[t + 448] = ga1 * (1.0f - wyg) + gb1 * wyg;
  sL[t] = la0 * (1.0f - wyl) + lb0 * wyl;
  sL[t + 448] = la1 * (1.0f - wyl) + lb1 * wyl;
  sL[t + 896] = la2 * (1.0f - wyl) + lb2s * wyl;
  if (t < 192) sL[t + 1344] = la3 * (1.0f - wyl) + lb3 * wyl;
  if (t < 64) sgr[t] = sg0 * (1.0f - wys) + sg1 * wys;
  __syncthreads();

  float rr_[2] = {rrA, rrB}, gg_[2] = {ggA, ggB}, bb_[2] = {bbA, bbB};
#pragma unroll
  for (int ip = 0; ip < 2; ++ip) {
    int w = ip * 448 + t;
    int hw = h * 896 + w;
    float r = rr_[ip];
    float g = gg_[ip];
    float bl = bb_[ip];
    float lr = srgb_lin(r), lg = srgb_lin(g), lb2 = srgb_lin(bl);
    float X = 0.412453f * lr + 0.357580f * lg + 0.180423f * lb2;
    float Y = 0.212671f * lr + 0.715160f * lg + 0.072169f * lb2;
    float Z = 0.019334f * lr + 0.119193f * lg + 0.950227f * lb2;
    float fx_ = labf(X * (1.0f / 0.950456f));
    float fy_ = labf(Y);
    float fz_ = labf(Z * (1.0f / 1.088754f));
    float gch = 0.50877193f * fy_ - 0.070175439f +
                1.0964912f * fabsf(fx_ - fy_) + 0.43859649f * fabsf(fy_ - fz_);
    gch = fminf(fmaxf(gch, 0.0f), 1.0f);
    float sx = fminf(fmaxf((w + 0.5f) * (1.0f / 14.0f) - 0.5f, 0.0f), 63.0f);
    int x0s = (int)sx;
    int x1s = x0s < 63 ? x0s + 1 : 63;
    float wxs = sx - (float)x0s;
    float gs = sgr[x0s] * (1.0f - wxs) + sgr[x1s] * wxs;
    float gg = 0.5f * gch + 0.5f * gs;
    __builtin_nontemporal_store(gg, &out[OUT_G + b * HWPIX + hw]);
    float fzc = fminf(fmaxf(gg * 7.0f, 0.0f), 7.0f);
    int z0 = (int)fzc;
    if (z0 > 7) z0 = 7;
    int z1 = z0 < 7 ? z0 + 1 : 7;
    float wz = fzc - (float)z0;
    float o0, o1, o2;
    slice_lds<8>(sG, w, z0, z1, wz, r, g, bl, o0, o1, o2);
    __builtin_nontemporal_store(o0, &out[(b * 3 + 0) * HWPIX + hw]);
    __builtin_nontemporal_store(o1, &out[(b * 3 + 1) * HWPIX + hw]);
    __builtin_nontemporal_store(o2, &out[(b * 3 + 2) * HWPIX + hw]);
    slice_lds<16>(sL, w, z0, z1, wz, r, g, bl, o0, o1, o2);
    __builtin_nontemporal_store(o0, &out[OUT_IL + (b * 3 + 0) * HWPIX + hw]);
    __builtin_nontemporal_store(o1, &out[OUT_IL + (b * 3 + 1) * HWPIX + hw]);
    __builtin_nontemporal_store(o2, &out[OUT_IL + (b * 3 + 2) * HWPIX + hw]);
  }
}

// ---------------------------------------------------------------------------
extern "C" void kernel_launch(void* const* d_in, const int* in_sizes, int n_in,
                              void* d_out, int out_size, void* d_ws,
                              size_t ws_size, hipStream_t stream) {
  const float* R = (const float*)d_in[0];
  const float* F = (const float*)d_in[1];
  const float* img = (const float*)d_in[2];
  const float* dino_w = (const float*)d_in[5];
  const float* dino_b = (const float*)d_in[6];
  const float* fus_w = (const float*)d_in[7];
  const float* fus_b = (const float*)d_in[8];
  const float* g1_w = (const float*)d_in[9];
  const float* g1_b = (const float*)d_in[10];
  const float* g2_w = (const float*)d_in[11];
  const float* g2_b = (const float*)d_in[12];
  const float* lw = (const float*)d_in[13];
  const float* lb = (const float*)d_in[14];
  const float* gw1 = (const float*)d_in[15];
  const float* gb1 = (const float*)d_in[16];
  const float* gw2 = (const float*)d_in[17];
  const float* gb2 = (const float*)d_in[18];
  float* out = (float*)d_out;
  float* ws = (float*)d_ws;

  float* Wt4 = ws + WS_WT4;
  float* bc = ws + WS_BC;
  float* pooled = ws + WS_POOL;
  float* gsem = ws + WS_GSEM;
  float* rg = ws + WS_RG;
  float* rl = ws + WS_RL;
  float* w1T = ws + WS_W1T;
  float* lwT = ws + WS_LWT;

  k_prep<<<643, 256, 0, stream>>>(fus_w, fus_b, dino_w, dino_b, gw1, lw,
                                  Wt4, bc, w1T, lwT);
  k_mid<<<1280, 256, 0, stream>>>(R, F, Wt4, bc, lwT, lb,
                                  pooled, out + OUT_GL, rl,
                                  w1T, gb1, gw2, gb2, gsem);
  k_head<<<96, 1024, 0, stream>>>(pooled, g1_w, g1_b, g2_w, g2_b,
                                  out + OUT_GG, rg);
  k_pixel<<<3584, 448, 0, stream>>>(img, gsem, rg, rl, out);
}